// Round 7
// baseline (254.069 us; speedup 1.0000x reference)
//
#include <hip/hip_runtime.h>
#include <hip/hip_bf16.h>

#define BSZ 32768
#define TT  3
#define OO  16

typedef __attribute__((ext_vector_type(8))) short bf16x8;
typedef __attribute__((ext_vector_type(4))) float f32x4;

__device__ __forceinline__ float bf2f(unsigned short u) {
  return __uint_as_float(((unsigned)u) << 16);
}
__device__ __forceinline__ unsigned short f2bf(float f) {
  unsigned u = __float_as_uint(f);
  u += 0x7fffu + ((u >> 16) & 1u);
  return (unsigned short)(u >> 16);
}
__device__ __forceinline__ unsigned pack2(unsigned short a, unsigned short b) {
  return (unsigned)a | ((unsigned)b << 16);
}

// Builds: Wf (GEMM1 B-frags, 320x512 split hi/lo), W2f (block-diag W2 frags),
// W3f (block-diag W3 frags). Zeroes the 98-float accumulator block.
__global__ void k_prep(const float* __restrict__ W1, const float* __restrict__ wg,
                       const float* __restrict__ W2, const float* __restrict__ W3,
                       unsigned short* __restrict__ Wfh, unsigned short* __restrict__ Wfl,
                       unsigned short* __restrict__ W2fh, unsigned short* __restrict__ W2fl,
                       unsigned short* __restrict__ W3fh, unsigned short* __restrict__ W3fl,
                       float* __restrict__ acc) {
  const int idx = blockIdx.x * 256 + threadIdx.x;
  if (blockIdx.x == 0 && threadIdx.x < 98) acc[threadIdx.x] = 0.f;
  if (idx < 163840) {
    const int nblk = idx >> 13, itg = (idx >> 9) & 15, lane = (idx >> 3) & 63, j = idx & 7;
    const int n = nblk * 16 + (lane & 15);
    const int k = itg * 32 + (lane >> 4) * 8 + j;
    float v = 0.f;
    if (n < 256) v = W1[(size_t)(n >> 4) * 8192 + k * 16 + (n & 15)];
    else if (n < 304) v = wg[(size_t)((n - 256) >> 4) * 8192 + k * 16 + ((n - 256) & 15)];
    const unsigned short hi = f2bf(v);
    Wfh[idx] = hi; Wfl[idx] = f2bf(v - bf2f(hi));
  } else if (idx < 163840 + 4096) {
    const int i = idx - 163840;
    const int nt = i >> 9, l = (i >> 3) & 63, j = i & 7;
    const int cc = l & 15, kw = ((l >> 4) << 3) + j;
    float v = 0.f;
    if ((kw >> 4) == (cc >> 3)) v = W2[(2 * nt + (cc >> 3)) * 128 + (kw & 15) * 8 + (cc & 7)];
    const unsigned short hi = f2bf(v);
    W2fh[i] = hi; W2fl[i] = f2bf(v - bf2f(hi));
  } else if (idx < 163840 + 4096 + 8192) {
    const int i = idx - 163840 - 4096;
    const int e = i >> 9, l = (i >> 3) & 63, j = i & 7;
    const int cc = l & 15, kw = ((l >> 4) << 3) + j;
    float v = 0.f;
    if ((kw >> 3) == (e & 3)) v = W3[e * 128 + (kw & 7) * 16 + cc];
    const unsigned short hi = f2bf(v);
    W3fh[i] = hi; W3fl[i] = f2bf(v - bf2f(hi));
  }
}

struct FSmem {
  union {
    struct {                               // phase a: x chunk (BK=128), frag order
      unsigned short xh[8][4][66][8];      // [m][it][lane(pad)][8]
      unsigned short xl[8][4][66][8];
    } a;
    struct {                               // phase b
      union {
        unsigned short h1A[8][8][64][8];   // 64KB  A-frags of h1 (m, kit, lane, j)
        float eoC[32][264];                // 33.8KB expert-output chunk (f32)
      } r2;
      unsigned short h2Ah[8][4][64][8];    // 32KB  h2 hi A-frags
      union {
        float lgs[128][52];                // gating logits
        unsigned short h2Al[8][4][64][8];  // 32KB  h2 lo (after gating done)
      } r1;
      float gvL[128][12];
      int   giL[128][12];
      float impL[48], loadL[48];
      int   nresc, resc[384];
      double resL[16];
    } b;
  } u;
  float rzrow[128];
};

// M=128/block, grid=256 (1 block/CU). GEMM1 (x@[W1|wg], 3-pass split bf16) +
// fused rz + gating + rescue + MFMA tail (block-diag GEMM2/GEMM3) + combine +
// last-block loss finalization.
__global__ __launch_bounds__(512, 2) void k_fused(
    const float* __restrict__ x, const unsigned short* __restrict__ Wfh,
    const unsigned short* __restrict__ Wfl, const unsigned short* __restrict__ W2fh,
    const unsigned short* __restrict__ W2fl, const unsigned short* __restrict__ W3fh,
    const unsigned short* __restrict__ W3fl, const float* __restrict__ b1,
    const float* __restrict__ bg, const float* __restrict__ wg,
    const float* __restrict__ b2, const float* __restrict__ b3,
    float* __restrict__ out, float* __restrict__ accg) {
  __shared__ FSmem sm;
  __shared__ int islast;
  const int tid = threadIdx.x;
  const int b0 = blockIdx.x * 128;
  const int w = tid >> 6, l = tid & 63;
  const int l15 = l & 15, quad = l >> 4;
  const int mh = w >> 2;   // row half: rows mh*64 ..
  const int cg = w & 3;    // col group: cols cg*80 ..
  const int srow = tid >> 2, skf = tid & 3;   // staging: row 0..127, 32-k window

  float* acc_imp = accg;          // [0:48)
  float* acc_load = accg + 48;    // [48:96)
  float* rz_acc = accg + 96;      // [96]

  f32x4 acc[4][5];
#pragma unroll
  for (int m = 0; m < 4; m++)
#pragma unroll
    for (int c = 0; c < 5; c++) acc[m][c] = (f32x4){0.f, 0.f, 0.f, 0.f};
  float rzsum = 0.f;

  float4 xv[8];
  auto load_x = [&](int ch) {
    const float* xp = &x[(size_t)(b0 + srow) * 512 + ch * 128 + skf * 32];
#pragma unroll
    for (int r = 0; r < 8; ++r) xv[r] = *(const float4*)(xp + r * 4);
  };
  auto cvt_store = [&]() {
#pragma unroll
    for (int q = 0; q < 4; ++q) {
      const float v[8] = {xv[2 * q].x, xv[2 * q].y, xv[2 * q].z, xv[2 * q].w,
                          xv[2 * q + 1].x, xv[2 * q + 1].y, xv[2 * q + 1].z, xv[2 * q + 1].w};
#pragma unroll
      for (int j = 0; j < 8; j++) rzsum += __expf(v[j]);
      unsigned short hh[8], ll[8];
#pragma unroll
      for (int j = 0; j < 8; j++) {
        hh[j] = f2bf(v[j]);
        ll[j] = f2bf(v[j] - bf2f(hh[j]));
      }
      uint4 ph, pl;
      ph.x = pack2(hh[0], hh[1]); ph.y = pack2(hh[2], hh[3]);
      ph.z = pack2(hh[4], hh[5]); ph.w = pack2(hh[6], hh[7]);
      pl.x = pack2(ll[0], ll[1]); pl.y = pack2(ll[2], ll[3]);
      pl.z = pack2(ll[4], ll[5]); pl.w = pack2(ll[6], ll[7]);
      const int lane = (srow & 15) + 16 * q;
      *(uint4*)&sm.u.a.xh[srow >> 4][skf][lane][0] = ph;
      *(uint4*)&sm.u.a.xl[srow >> 4][skf][lane][0] = pl;
    }
  };

  // W ring, depth 4 (MFMA cover ~240cyc >= L2 latency)
  bf16x8 rbh[4], rbl[4];
#pragma unroll
  for (int s = 0; s < 4; ++s) {
    const size_t o = ((size_t)((cg * 5 + s) * 16) * 64 + l) * 8;  // itg=0, c=s
    rbh[s] = *(const bf16x8*)&Wfh[o];
    rbl[s] = *(const bf16x8*)&Wfl[o];
  }
  load_x(0);

#pragma unroll 1
  for (int ch = 0; ch < 4; ++ch) {
    if (ch) __syncthreads();        // prev chunk's MFMA LDS reads done
    cvt_store();                    // waits on xv (prefetched a chunk ago)
    __syncthreads();
    if (ch < 3) load_x(ch + 1);     // issue next chunk's HBM loads now
#pragma unroll
    for (int it = 0; it < 4; ++it) {
      bf16x8 ah[4], al[4];
#pragma unroll
      for (int m = 0; m < 4; m++) {
        ah[m] = *(const bf16x8*)&sm.u.a.xh[mh * 4 + m][it][l][0];
        al[m] = *(const bf16x8*)&sm.u.a.xl[mh * 4 + m][it][l][0];
      }
#pragma unroll
      for (int c = 0; c < 5; ++c) {
        const int j = it * 5 + c;                 // compile-time
        bf16x8 bh = rbh[j & 3], bl = rbl[j & 3];
        const int jn = j + 4;
        if (ch * 20 + jn < 80) {
          const int itgn = ch * 4 + jn / 5;       // jn/5, jn%5 compile-time
          const int cn = jn % 5;
          const size_t o = ((size_t)((cg * 5 + cn) * 16 + itgn) * 64 + l) * 8;
          rbh[j & 3] = *(const bf16x8*)&Wfh[o];
          rbl[j & 3] = *(const bf16x8*)&Wfl[o];
        }
#pragma unroll
        for (int m = 0; m < 4; m++)
          acc[m][c] = __builtin_amdgcn_mfma_f32_16x16x32_bf16(ah[m], bh, acc[m][c], 0, 0, 0);
#pragma unroll
        for (int m = 0; m < 4; m++)
          acc[m][c] = __builtin_amdgcn_mfma_f32_16x16x32_bf16(al[m], bh, acc[m][c], 0, 0, 0);
#pragma unroll
        for (int m = 0; m < 4; m++)
          acc[m][c] = __builtin_amdgcn_mfma_f32_16x16x32_bf16(ah[m], bl, acc[m][c], 0, 0, 0);
      }
    }
  }

  // router-z: 4 threads/row
  rzsum += __shfl_xor(rzsum, 1);
  rzsum += __shfl_xor(rzsum, 2);
  if (skf == 0) sm.rzrow[srow] = rzsum;
  __syncthreads();  // MFMA reads done; phase-b union reuse safe
  if (tid < 128) {
    float vv = __logf(sm.rzrow[tid]);
#pragma unroll
    for (int off = 32; off; off >>= 1) vv += __shfl_xor(vv, off);
    if ((tid & 63) == 0) atomicAdd(rz_acc, vv);
  }

  // ---- epilogue: h1 -> h1A (A-frag bf16), logits -> lgs ----
#pragma unroll
  for (int m = 0; m < 4; m++)
#pragma unroll
    for (int c = 0; c < 5; c++) {
      const int col = cg * 80 + c * 16 + l15;
      if (col < 256) {
        const float bb = b1[col];
#pragma unroll
        for (int reg = 0; reg < 4; reg++) {
          const int ri = quad * 4 + reg;
          sm.u.b.r2.h1A[mh * 4 + m][col >> 5][ri + 16 * ((col & 31) >> 3)][col & 7] =
              f2bf(fmaxf(acc[m][c][reg] + bb, 0.f));
        }
      } else if (col < 304) {
        const float bb = bg[col - 256];
#pragma unroll
        for (int reg = 0; reg < 4; reg++) {
          const int row = (mh * 4 + m) * 16 + quad * 4 + reg;
          sm.u.b.r1.lgs[row][col - 256] = acc[m][c][reg] + bb;
        }
      }
    }
  if (tid < 48) { sm.u.b.impL[tid] = 0.f; sm.u.b.loadL[tid] = 0.f; }
  if (tid == 0) sm.u.b.nresc = 0;
  __syncthreads();

  // ---- gating: 384 threads = 3 tasks x 128 rows (masked top-k) ----
  if (tid < 384) {
    const int r = tid & 127, tk = tid >> 7;
    float v[16];
#pragma unroll
    for (int e = 0; e < 16; e++) v[e] = sm.u.b.r1.lgs[r][tk * 16 + e];
    unsigned used = 0;
    int idx[5]; float val[5];
#pragma unroll
    for (int p = 0; p < 5; p++) {
      float best = -INFINITY; int bi = 0;
#pragma unroll
      for (int e = 0; e < 16; e++) {
        const float ve = ((used >> e) & 1u) ? -INFINITY : v[e];
        if (ve > best) { best = ve; bi = e; }
      }
      idx[p] = bi; val[p] = best; used |= 1u << bi;
    }
    if (val[3] - val[4] < 3e-3f) {
      const int s = atomicAdd(&sm.u.b.nresc, 1);
      sm.u.b.resc[s] = (r << 2) | tk;
    }
    const float m = val[0];
    float ex[4], sum = 0.f;
#pragma unroll
    for (int p = 0; p < 4; p++) { ex[p] = __expf(val[p] - m); sum += ex[p]; }
#pragma unroll
    for (int p = 0; p < 4; p++) {
      const float g = ex[p] / sum;
      sm.u.b.gvL[r][tk * 4 + p] = g;
      sm.u.b.giL[r][tk * 4 + p] = idx[p];
      atomicAdd(&sm.u.b.impL[tk * 16 + idx[p]], g);
      atomicAdd(&sm.u.b.loadL[tk * 16 + idx[p]], 1.f);
    }
  }
  __syncthreads();

  // ---- cooperative f64 rescue ----
  const int nr = sm.u.b.nresc;
  for (int i = 0; i < nr; i++) {
    const int st = sm.u.b.resc[i];
    const int r = st >> 2, tk = st & 3;
    if (tid < 256) {
      const int e = tid >> 4, part = tid & 15;
      const float* xr2 = &x[(size_t)(b0 + r) * 512];
      const float* wgc = &wg[(size_t)tk * 8192 + e];
      double a = 0.0;
      for (int d = part * 32; d < part * 32 + 32; d++)
        a += (double)xr2[d] * (double)wgc[(size_t)d * 16];
#pragma unroll
      for (int off = 1; off < 16; off <<= 1) a += __shfl_xor(a, off);
      if (part == 0) sm.u.b.resL[e] = a + (double)bg[tk * 16 + e];
    }
    __syncthreads();
    if (tid == 0) {
      for (int p = 0; p < 4; p++) {
        sm.u.b.impL[tk * 16 + sm.u.b.giL[r][tk * 4 + p]] -= sm.u.b.gvL[r][tk * 4 + p];
        sm.u.b.loadL[tk * 16 + sm.u.b.giL[r][tk * 4 + p]] -= 1.f;
      }
      unsigned used = 0;
      int idx[4]; float val[4];
      for (int p = 0; p < 4; p++) {
        double best = -1e300; int bi = 0;
        for (int e2 = 0; e2 < 16; e2++) {
          if ((used >> e2) & 1u) continue;
          const double ve = sm.u.b.resL[e2];
          if (ve > best) { best = ve; bi = e2; }
        }
        idx[p] = bi; val[p] = (float)best; used |= 1u << bi;
      }
      const float m = val[0];
      float ex[4], sum = 0.f;
      for (int p = 0; p < 4; p++) { ex[p] = __expf(val[p] - m); sum += ex[p]; }
      for (int p = 0; p < 4; p++) {
        const float g = ex[p] / sum;
        sm.u.b.gvL[r][tk * 4 + p] = g;
        sm.u.b.giL[r][tk * 4 + p] = idx[p];
        sm.u.b.impL[tk * 16 + idx[p]] += g;
        sm.u.b.loadL[tk * 16 + idx[p]] += 1.f;
      }
    }
    __syncthreads();
  }
  if (tid < 48) {
    atomicAdd(&acc_imp[tid], sm.u.b.impL[tid]);
    atomicAdd(&acc_load[tid], sm.u.b.loadL[tid]);
  }
  __syncthreads();  // lgs dead; h2Al may overwrite it

  // ---- GEMM2: h2 = relu(h1 @ blockdiag(W2) + b2), split hi/lo to LDS ----
  {
    const bf16x8 w2h = *(const bf16x8*)&W2fh[(size_t)(w * 64 + l) * 8];
    const bf16x8 w2l = *(const bf16x8*)&W2fl[(size_t)(w * 64 + l) * 8];
    const float b2v = b2[w * 16 + l15];
    const int kit = w >> 1;
    const int lane2b = 16 * (2 * (w & 1) + (l15 >> 3));
    const int j2 = l15 & 7;
#pragma unroll
    for (int m = 0; m < 8; m++) {
      const bf16x8 a = *(const bf16x8*)&sm.u.b.r2.h1A[m][w][l][0];
      f32x4 a2 = __builtin_amdgcn_mfma_f32_16x16x32_bf16(a, w2h, (f32x4){0.f, 0.f, 0.f, 0.f}, 0, 0, 0);
      a2 = __builtin_amdgcn_mfma_f32_16x16x32_bf16(a, w2l, a2, 0, 0, 0);
#pragma unroll
      for (int reg = 0; reg < 4; reg++) {
        const float val = fmaxf(a2[reg] + b2v, 0.f);
        const unsigned short hi = f2bf(val);
        const int lane2 = (quad * 4 + reg) + lane2b;
        sm.u.b.h2Ah[m][kit][lane2][j2] = hi;
        sm.u.b.r1.h2Al[m][kit][lane2][j2] = f2bf(val - bf2f(hi));
      }
    }
  }
  __syncthreads();  // h2A ready; h1A dead -> eoC may reuse

  // ---- GEMM3 + combine, 32-row chunks ----
  {
    bf16x8 w3h[2], w3l[2];
    float b3v[2];
#pragma unroll
    for (int ee = 0; ee < 2; ee++) {
      const int e = w + ee * 8;
      w3h[ee] = *(const bf16x8*)&W3fh[(size_t)(e * 64 + l) * 8];
      w3l[ee] = *(const bf16x8*)&W3fl[(size_t)(e * 64 + l) * 8];
      b3v[ee] = b3[e * 16 + l15];
    }
#pragma unroll 1
    for (int p = 0; p < 4; ++p) {
#pragma unroll
      for (int mm = 0; mm < 2; ++mm) {
        const int m = p * 2 + mm;
#pragma unroll
        for (int ee = 0; ee < 2; ++ee) {
          const int e = w + ee * 8;
          const bf16x8 hh = *(const bf16x8*)&sm.u.b.h2Ah[m][e >> 2][l][0];
          const bf16x8 hl = *(const bf16x8*)&sm.u.b.r1.h2Al[m][e >> 2][l][0];
          f32x4 a3 = __builtin_amdgcn_mfma_f32_16x16x32_bf16(hh, w3h[ee], (f32x4){0.f, 0.f, 0.f, 0.f}, 0, 0, 0);
          a3 = __builtin_amdgcn_mfma_f32_16x16x32_bf16(hl, w3h[ee], a3, 0, 0, 0);
          a3 = __builtin_amdgcn_mfma_f32_16x16x32_bf16(hh, w3l[ee], a3, 0, 0, 0);
#pragma unroll
          for (int reg = 0; reg < 4; reg++)
            sm.u.b.r2.eoC[mm * 16 + quad * 4 + reg][e * 16 + l15] = fmaxf(a3[reg] + b3v[ee], 0.f);
        }
      }
      __syncthreads();
      {
        const int row16 = tid >> 4, o = tid & 15;
        const int r_abs = p * 32 + row16;
#pragma unroll
        for (int tk = 0; tk < TT; tk++) {
          float y = 0.f;
#pragma unroll
          for (int pp = 0; pp < 4; pp++) {
            const float g = sm.u.b.gvL[r_abs][tk * 4 + pp];
            const int gi = sm.u.b.giL[r_abs][tk * 4 + pp];
            y += g * sm.u.b.r2.eoC[row16][gi * 16 + o];
          }
          out[((size_t)tk * BSZ + b0 + r_abs) * OO + o] = y;
        }
      }
      __syncthreads();
    }
  }

  // ---- last-block loss finalization ----
  __threadfence();
  if (tid == 0) islast = (atomicAdd((int*)(accg + 97), 1) == 255);
  __syncthreads();
  if (islast) {
    float* fin = &sm.u.b.gvL[0][0];
    if (tid < 97) fin[tid] = atomicAdd(&accg[tid], 0.f);  // coherent read
    __syncthreads();
    if (tid == 0) {
      double lb = 0.0;
      for (int t = 0; t < TT; t++) {
        const float* imp = &fin[t * 16];
        const float* ld = &fin[48 + t * 16];
        double si = 0, sl = 0, dot = 0;
        for (int e2 = 0; e2 < 16; e2++) {
          si += imp[e2]; sl += ld[e2]; dot += (double)imp[e2] * ld[e2];
        }
        const double mi = si / 16.0, ml = sl / 16.0;
        double vi = 0, vl = 0;
        for (int e2 = 0; e2 < 16; e2++) {
          const double di = imp[e2] - mi, dl = ld[e2] - ml;
          vi += di * di; vl += dl * dl;
        }
        vi /= 15.0; vl /= 15.0;
        lb += (vi / (mi * mi + 1e-10) + vl / (ml * ml + 1e-10)) * 0.01
            + 16.0 * dot / (double)BSZ * 0.01;
      }
      float* out_tail = out + (size_t)TT * BSZ * OO;
      out_tail[0] = (float)lb;
      out_tail[1] = (float)(3.0 * ((double)fin[96] / (double)BSZ) * 0.001);
    }
  }
}

extern "C" void kernel_launch(void* const* d_in, const int* in_sizes, int n_in,
                              void* d_out, int out_size, void* d_ws, size_t ws_size,
                              hipStream_t stream) {
  const float* x  = (const float*)d_in[0];
  const float* wg = (const float*)d_in[1];
  const float* bg = (const float*)d_in[2];
  const float* W1 = (const float*)d_in[3];
  const float* b1 = (const float*)d_in[4];
  const float* W2 = (const float*)d_in[5];
  const float* b2 = (const float*)d_in[6];
  const float* W3 = (const float*)d_in[7];
  const float* b3 = (const float*)d_in[8];
  float* out = (float*)d_out;

  char* wsb = (char*)d_ws;
  unsigned short* Wfh  = (unsigned short*)wsb;              // 327,680 B
  unsigned short* Wfl  = (unsigned short*)(wsb + 327680);   // 327,680 B
  unsigned short* W2fh = (unsigned short*)(wsb + 655360);   //   8,192 B
  unsigned short* W2fl = (unsigned short*)(wsb + 663552);   //   8,192 B
  unsigned short* W3fh = (unsigned short*)(wsb + 671744);   //  16,384 B
  unsigned short* W3fl = (unsigned short*)(wsb + 688128);   //  16,384 B
  float* acc = (float*)(wsb + 704512);                      // 98 floats

  k_prep<<<dim3(688), dim3(256), 0, stream>>>(W1, wg, W2, W3, Wfh, Wfl,
                                              W2fh, W2fl, W3fh, W3fl, acc);
  k_fused<<<dim3(256), dim3(512), 0, stream>>>(x, Wfh, Wfl, W2fh, W2fl, W3fh, W3fl,
                                               b1, bg, wg, b2, b3, out, acc);
}